// Round 2
// baseline (625.244 us; speedup 1.0000x reference)
//
#include <hip/hip_runtime.h>
#include <stdint.h>
#include <math.h>

#define B_  4
#define S_  2048
#define H_  2048
#define NH_ 16
#define HD_ 128
#define M_  (B_*S_)     // 8192 rows
#define N3_ (3*H_)      // 6144
#define NQT_ (S_/64)    // 32 q-tiles of 64 rows
#define NT_ (H_/64)     // 32 K-tiles for the GEMMs

typedef __attribute__((ext_vector_type(8))) short short8;
typedef __attribute__((ext_vector_type(4))) float floatx4;
typedef unsigned int u32;

__device__ __forceinline__ unsigned short f2bf(float f) {
  unsigned u = __float_as_uint(f);
  u += 0x7FFF + ((u >> 16) & 1);          // round-to-nearest-even
  return (unsigned short)(u >> 16);
}

// async 16B global -> LDS (global_load_lds_dwordx4). LDS dest must be
// wave-uniform base + lane*16 (no per-lane scatter / padding!).
__device__ __forceinline__ void gl2lds16(const void* g, void* l) {
  __builtin_amdgcn_global_load_lds(
      (const __attribute__((address_space(1))) u32*)g,
      (__attribute__((address_space(3))) u32*)l, 16, 0, 0);
}

// ---------------------------------------------------------------- LayerNorm
__global__ __launch_bounds__(256) void ln_kernel(
    const float* __restrict__ x, const float* __restrict__ w,
    const float* __restrict__ b, unsigned short* __restrict__ xn) {
  int row = blockIdx.x;
  int t = threadIdx.x;
  const float* xr = x + (size_t)row * H_;
  float4 v0 = *(const float4*)(xr + t * 4);
  float4 v1 = *(const float4*)(xr + 1024 + t * 4);
  float s  = v0.x + v0.y + v0.z + v0.w + v1.x + v1.y + v1.z + v1.w;
  float sq = v0.x*v0.x + v0.y*v0.y + v0.z*v0.z + v0.w*v0.w
           + v1.x*v1.x + v1.y*v1.y + v1.z*v1.z + v1.w*v1.w;
  #pragma unroll
  for (int m = 32; m; m >>= 1) { s += __shfl_xor(s, m); sq += __shfl_xor(sq, m); }
  __shared__ float red[8];
  int wv = t >> 6;
  if ((t & 63) == 0) { red[wv * 2] = s; red[wv * 2 + 1] = sq; }
  __syncthreads();
  s  = red[0] + red[2] + red[4] + red[6];
  sq = red[1] + red[3] + red[5] + red[7];
  float mu  = s * (1.0f / H_);
  float var = sq * (1.0f / H_) - mu * mu;
  float rs  = rsqrtf(var + 1e-5f);

  float4 w0 = *(const float4*)(w + t * 4);
  float4 b0 = *(const float4*)(b + t * 4);
  float4 w1 = *(const float4*)(w + 1024 + t * 4);
  float4 b1 = *(const float4*)(b + 1024 + t * 4);
  ushort4 o0, o1;
  o0.x = f2bf((v0.x - mu) * rs * w0.x + b0.x);
  o0.y = f2bf((v0.y - mu) * rs * w0.y + b0.y);
  o0.z = f2bf((v0.z - mu) * rs * w0.z + b0.z);
  o0.w = f2bf((v0.w - mu) * rs * w0.w + b0.w);
  o1.x = f2bf((v1.x - mu) * rs * w1.x + b1.x);
  o1.y = f2bf((v1.y - mu) * rs * w1.y + b1.y);
  o1.z = f2bf((v1.z - mu) * rs * w1.z + b1.z);
  o1.w = f2bf((v1.w - mu) * rs * w1.w + b1.w);
  unsigned short* orow = xn + (size_t)row * H_;
  *(ushort4*)(orow + t * 4) = o0;
  *(ushort4*)(orow + 1024 + t * 4) = o1;
}

// ------------------------------------------- fp32 [R][C] -> bf16 [C][R] (Wt)
__global__ __launch_bounds__(256) void transpose_f2b(
    const float* __restrict__ in, unsigned short* __restrict__ out,
    int R, int C) {
  __shared__ float tile[32][33];
  int tx = threadIdx.x & 31, ty = threadIdx.x >> 5;   // ty 0..7
  int c0 = blockIdx.x * 32, r0 = blockIdx.y * 32;
  #pragma unroll
  for (int i = 0; i < 32; i += 8)
    tile[ty + i][tx] = in[(size_t)(r0 + ty + i) * C + c0 + tx];
  __syncthreads();
  #pragma unroll
  for (int i = 0; i < 32; i += 8)
    out[(size_t)(c0 + ty + i) * R + r0 + tx] = f2bf(tile[tx][ty + i]);
}

// ===================================================================
// 256x256 8-phase GEMM core (HK-style schedule in plain HIP, per m201).
// See R0 comment block for region/phase/vmcnt derivation (unchanged).
// ===================================================================
__device__ __forceinline__ void gemm256_acc(
    const unsigned short* __restrict__ A, const unsigned short* __restrict__ Bt,
    int m0, int n0, unsigned short (*sh)[16384], floatx4 (&acc)[8][4]) {
  const int t = threadIdx.x;
  const int lane = t & 63, wv = t >> 6;
  const int l15 = lane & 15, quad = lane >> 4;
  const int wm = wv >> 2, wn = wv & 3;
  const int x7 = l15 & 7;

  // read-side bases (shorts); frag (i,ks) = base + i*1024 + kx[ks]
  const int aRB = (wm * 128 + l15) * 64;
  const int bRB = (wn * 64 + l15) * 64;
  const int kx0 = ((0 + quad) ^ x7) * 8;
  const int kx1 = ((4 + quad) ^ x7) * 8;

  // stage-side: thread t covers (row r = t>>3, chunk cc = t&7) of each region
  const int r = t >> 3, cc = t & 7;
  const int scol = (cc ^ (r & 7)) * 8;                 // swizzled SOURCE chunk
  const unsigned short* aSrc = A + (size_t)(m0 + r) * H_ + scol;
  const int btr = (r >> 5) * 64 + (r & 31);            // B-j01 tile row
  const unsigned short* bSrc = Bt + (size_t)(n0 + btr) * H_ + scol;
  const int aDst = t * 8;                              // shorts, lane-linear
  const int bDst = (r >> 5) * 4096 + (r & 31) * 64 + cc * 8;

  // sh[buf*2] = A tile, sh[buf*2+1] = B tile
  auto stageA = [&](int kt, int reg, int buf) {        // reg: 0=even 1=odd
    const unsigned short* s = aSrc + (size_t)(reg * 64) * H_ + kt * 64;
    unsigned short* d = sh[buf * 2] + aDst + reg * 4096;
    gl2lds16(s, d);
    gl2lds16(s + (size_t)128 * H_, d + 8192);
  };
  auto stageB = [&](int kt, int reg, int buf) {        // reg: 0=j01 1=j23
    const unsigned short* s = bSrc + (size_t)(reg * 32) * H_ + kt * 64;
    unsigned short* d = sh[buf * 2 + 1] + bDst + reg * 2048;
    gl2lds16(s, d);
    gl2lds16(s + (size_t)128 * H_, d + 8192);
  };

  #pragma unroll
  for (int i = 0; i < 8; i++)
    #pragma unroll
    for (int j = 0; j < 4; j++) acc[i][j] = (floatx4){0.f, 0.f, 0.f, 0.f};

  // prologue: tile0 fully, tile1 minus B-j23 (issued at tile0 p0)
  stageA(0, 0, 0); stageB(0, 0, 0); stageA(0, 1, 0); stageB(0, 1, 0);
  stageA(1, 0, 1); stageB(1, 0, 1); stageA(1, 1, 1);
  asm volatile("s_waitcnt vmcnt(6)" ::: "memory");     // tile0 landed
  __builtin_amdgcn_s_barrier();

  short8 aR[4][2], b01[2][2], b23[2][2];

  for (int n = 0; n < NT_; ++n) {
    const int buf = n & 1;
    const unsigned short* Ab = sh[buf * 2];
    const unsigned short* Bb = sh[buf * 2 + 1];

    // ---- phase 0: read A-even + B-j01 (12 ds_read); MFMA i0-3 x j0-1
    #pragma unroll
    for (int i = 0; i < 4; ++i) {
      aR[i][0] = *(const short8*)(Ab + aRB + i * 1024 + kx0);
      aR[i][1] = *(const short8*)(Ab + aRB + i * 1024 + kx1);
    }
    #pragma unroll
    for (int j = 0; j < 2; ++j) {
      b01[j][0] = *(const short8*)(Bb + bRB + j * 1024 + kx0);
      b01[j][1] = *(const short8*)(Bb + bRB + j * 1024 + kx1);
    }
    if (n + 1 < NT_) stageB(n + 1, 1, buf ^ 1);
    asm volatile("s_waitcnt lgkmcnt(8)" ::: "memory");
    __builtin_amdgcn_s_barrier();
    asm volatile("s_waitcnt lgkmcnt(0)" ::: "memory");
    __builtin_amdgcn_sched_barrier(0);
    __builtin_amdgcn_s_setprio(1);
    #pragma unroll
    for (int i = 0; i < 4; ++i)
      #pragma unroll
      for (int j = 0; j < 2; ++j) {
        acc[i][j] = __builtin_amdgcn_mfma_f32_16x16x32_bf16(aR[i][0], b01[j][0], acc[i][j], 0, 0, 0);
        acc[i][j] = __builtin_amdgcn_mfma_f32_16x16x32_bf16(aR[i][1], b01[j][1], acc[i][j], 0, 0, 0);
      }
    __builtin_amdgcn_s_setprio(0);
    __builtin_amdgcn_s_barrier();

    // ---- phase 1: read B-j23 (4); MFMA i0-3 x j2-3
    #pragma unroll
    for (int j = 0; j < 2; ++j) {
      b23[j][0] = *(const short8*)(Bb + bRB + (j + 2) * 1024 + kx0);
      b23[j][1] = *(const short8*)(Bb + bRB + (j + 2) * 1024 + kx1);
    }
    if (n + 2 < NT_) stageA(n + 2, 0, buf);
    __builtin_amdgcn_s_barrier();
    asm volatile("s_waitcnt lgkmcnt(0)" ::: "memory");
    __builtin_amdgcn_sched_barrier(0);
    __builtin_amdgcn_s_setprio(1);
    #pragma unroll
    for (int i = 0; i < 4; ++i)
      #pragma unroll
      for (int j = 0; j < 2; ++j) {
        acc[i][j + 2] = __builtin_amdgcn_mfma_f32_16x16x32_bf16(aR[i][0], b23[j][0], acc[i][j + 2], 0, 0, 0);
        acc[i][j + 2] = __builtin_amdgcn_mfma_f32_16x16x32_bf16(aR[i][1], b23[j][1], acc[i][j + 2], 0, 0, 0);
      }
    __builtin_amdgcn_s_setprio(0);
    __builtin_amdgcn_s_barrier();

    // ---- phase 2: read A-odd (8); MFMA i4-7 x j0-1
    #pragma unroll
    for (int i = 0; i < 4; ++i) {
      aR[i][0] = *(const short8*)(Ab + aRB + (i + 4) * 1024 + kx0);
      aR[i][1] = *(const short8*)(Ab + aRB + (i + 4) * 1024 + kx1);
    }
    if (n + 2 < NT_) stageB(n + 2, 0, buf);
    __builtin_amdgcn_s_barrier();
    asm volatile("s_waitcnt lgkmcnt(0)" ::: "memory");
    __builtin_amdgcn_sched_barrier(0);
    __builtin_amdgcn_s_setprio(1);
    #pragma unroll
    for (int i = 0; i < 4; ++i)
      #pragma unroll
      for (int j = 0; j < 2; ++j) {
        acc[i + 4][j] = __builtin_amdgcn_mfma_f32_16x16x32_bf16(aR[i][0], b01[j][0], acc[i + 4][j], 0, 0, 0);
        acc[i + 4][j] = __builtin_amdgcn_mfma_f32_16x16x32_bf16(aR[i][1], b01[j][1], acc[i + 4][j], 0, 0, 0);
      }
    __builtin_amdgcn_s_setprio(0);
    __builtin_amdgcn_s_barrier();

    // ---- phase 3: no reads; MFMA i4-7 x j2-3; counted vmcnt once per tile
    if (n + 2 < NT_) stageA(n + 2, 1, buf);
    __builtin_amdgcn_s_barrier();
    __builtin_amdgcn_s_setprio(1);
    #pragma unroll
    for (int i = 0; i < 4; ++i)
      #pragma unroll
      for (int j = 0; j < 2; ++j) {
        acc[i + 4][j + 2] = __builtin_amdgcn_mfma_f32_16x16x32_bf16(aR[i][0], b23[j][0], acc[i + 4][j + 2], 0, 0, 0);
        acc[i + 4][j + 2] = __builtin_amdgcn_mfma_f32_16x16x32_bf16(aR[i][1], b23[j][1], acc[i + 4][j + 2], 0, 0, 0);
      }
    __builtin_amdgcn_s_setprio(0);
    if (n + 2 < NT_) asm volatile("s_waitcnt vmcnt(6)" ::: "memory");
    else             asm volatile("s_waitcnt vmcnt(0)" ::: "memory");
    __builtin_amdgcn_s_barrier();
  }
}

// XCD-aware work mapping with L2-correct loop order. HW: block bid runs on
// XCD bid%8. XCD x owns m-panels [4x,4x+4) (A set = 4MB, L2-resident) and
// sweeps all n-panels n-OUTER m-INNER; at any instant all 8 XCDs stream the
// same few B-panels (one L3 fill, 8 L2 copies). Requires gridDim.y == 32.
__device__ __forceinline__ void xcd_map(int& m0, int& n0) {
  int bid = blockIdx.y * gridDim.x + blockIdx.x;
  int xcd = bid & 7, loc = bid >> 3;
  m0 = ((xcd << 2) | (loc & 3)) * 256;
  n0 = (loc >> 2) * 256;
}

// ---------------------------------------------------------------- QKV GEMM
__global__ __launch_bounds__(512, 2) void qkv_gemm(
    const unsigned short* __restrict__ A, const unsigned short* __restrict__ Bt,
    const float* __restrict__ bias,
    unsigned short* __restrict__ qw, unsigned short* __restrict__ kw,
    unsigned short* __restrict__ vtw) {
  __shared__ unsigned short sh[4][16384];   // 128 KiB
  int m0, n0;
  xcd_map(m0, n0);

  floatx4 acc[8][4];
  gemm256_acc(A, Bt, m0, n0, sh, acc);

  int t = threadIdx.x, lane = t & 63, wv = t >> 6;
  int l15 = lane & 15, quad = lane >> 4;
  int wm = wv >> 2, wn = wv & 3;
  int sec = n0 >> 11;                       // 0:Q 1:K 2:V (256 | 2048)
  #pragma unroll
  for (int j = 0; j < 4; ++j) {
    int nn = n0 + wn * 64 + j * 16 + l15;
    int h = (nn >> 7) & 15;
    int d = nn & 127;
    float bval = bias[nn];
    #pragma unroll
    for (int i = 0; i < 8; ++i) {
      int m = m0 + wm * 128 + i * 16 + quad * 4;   // 4 consecutive rows
      int bb = m >> 11, s = m & 2047;
      int bh = bb * NH_ + h;
      if (sec == 2) {
        ushort4 pv;
        pv.x = f2bf(acc[i][j][0] + bval); pv.y = f2bf(acc[i][j][1] + bval);
        pv.z = f2bf(acc[i][j][2] + bval); pv.w = f2bf(acc[i][j][3] + bval);
        *(ushort4*)(vtw + ((size_t)bh * HD_ + d) * S_ + s) = pv;
      } else {
        unsigned short* dst = (sec == 0 ? qw : kw) + ((size_t)bh * S_ + s) * HD_ + d;
        #pragma unroll
        for (int reg = 0; reg < 4; reg++)
          dst[(size_t)reg * HD_] = f2bf(acc[i][j][reg] + bval);
      }
    }
  }
}

// ----------------------------------------------------------- Proj GEMM + res
__global__ __launch_bounds__(512, 2) void proj_gemm(
    const unsigned short* __restrict__ A, const unsigned short* __restrict__ Bt,
    const float* __restrict__ bias, const float* __restrict__ resid,
    float* __restrict__ out) {
  __shared__ unsigned short sh[4][16384];
  int m0, n0;
  xcd_map(m0, n0);

  floatx4 acc[8][4];
  gemm256_acc(A, Bt, m0, n0, sh, acc);

  int t = threadIdx.x, lane = t & 63, wv = t >> 6;
  int l15 = lane & 15, quad = lane >> 4;
  int wm = wv >> 2, wn = wv & 3;
  #pragma unroll
  for (int j = 0; j < 4; ++j) {
    int nn = n0 + wn * 64 + j * 16 + l15;
    float bval = bias[nn];
    #pragma unroll
    for (int i = 0; i < 8; ++i) {
      int m = m0 + wm * 128 + i * 16 + quad * 4;
      #pragma unroll
      for (int reg = 0; reg < 4; ++reg)
        out[(size_t)(m + reg) * H_ + nn] =
            acc[i][j][reg] + bval + resid[(size_t)(m + reg) * H_ + nn];
    }
  }
}

// ------------------------------------------------------- causal flash attn
// R1: + s_setprio around MFMA clusters (T5, attn +4-7% m191)
//     + defer-max RESCALE_THRESHOLD=8 (T13, +5% m214v23, numerics m239)
__global__ __launch_bounds__(256) void attn_kernel(
    const unsigned short* __restrict__ qw, const unsigned short* __restrict__ kw,
    const unsigned short* __restrict__ vtw, unsigned short* __restrict__ ow) {
  __shared__ unsigned short Klds[64 * 136];   // [key 64][d 128 + pad]
  __shared__ unsigned short Vtl[128 * 72];    // [d 128][key 64 + pad]
  __shared__ unsigned short Pl[4][16 * 72];   // [wave][q 16][key 64 + pad]
  int pr = blockIdx.x, bh = blockIdx.y;
  int t = threadIdx.x, lane = t & 63, wv = t >> 6;
  int l15 = lane & 15, quad = lane >> 4;
  int h = bh & 15, bb = bh >> 4;

  const float scale = 0.08838834764831845f;
  int krr = t >> 4, kcc = (t & 15) * 8;       // K staging: 16 lanes/row
  int vdd = t >> 3, vss = (t & 7) * 8;        // Vt staging: 8 lanes/row
  unsigned short* plw = &Pl[wv][0];
  const unsigned short* kgb = kw + ((size_t)bh * S_ + krr) * HD_ + kcc;
  const unsigned short* vgb = vtw + ((size_t)bh * HD_ + vdd) * S_ + vss;

  short8 kreg[4], vreg[4];
  auto load_stage = [&](int kb) {
    #pragma unroll
    for (int c = 0; c < 4; c++) {
      kreg[c] = *(const short8*)(kgb + (size_t)(kb + c * 16) * HD_);
      vreg[c] = *(const short8*)(vgb + (size_t)(c * 32) * S_ + kb);
    }
  };

  #pragma unroll 1
  for (int half = 0; half < 2; half++) {
    int qt = half ? (NQT_ - 1 - pr) : pr;
    int qr = qt * 64 + wv * 16;
    int q = qr + l15;                         // this lane's q-row

    short8 qf[4];
    {
      const unsigned short* qbase = qw + ((size_t)bh * S_ + q) * HD_ + quad * 8;
      #pragma unroll
      for (int ks = 0; ks < 4; ks++)
        qf[ks] = *(const short8*)(qbase + ks * 32);
    }

    float m_i = -INFINITY, l_i = 0.f;
    floatx4 o[8];
    #pragma unroll
    for (int ht = 0; ht < 8; ht++) o[ht] = (floatx4){0.f, 0.f, 0.f, 0.f};

    load_stage(0);                            // prime the pipeline
    #pragma unroll 1
    for (int kt = 0; kt <= qt; kt++) {
      int kb = kt * 64;
      __syncthreads();                        // prev tile's LDS reads done
      #pragma unroll
      for (int c = 0; c < 4; c++) {
        *(short8*)(Klds + (c * 16 + krr) * 136 + kcc) = kreg[c];
        *(short8*)(Vtl + (c * 32 + vdd) * 72 + vss) = vreg[c];
      }
      __syncthreads();                        // tile visible to all waves
      if (kt < qt) load_stage(kb + 64);       // prefetch overlaps compute

      floatx4 sv[4];
      __builtin_amdgcn_s_setprio(1);
      #pragma unroll
      for (int jm = 0; jm < 4; jm++) {
        sv[jm] = (floatx4){0.f, 0.f, 0.f, 0.f};
        #pragma unroll
        for (int ks = 0; ks < 4; ks++) {
          short8 kf = *(const short8*)(Klds + (jm * 16 + l15) * 136 + ks * 32 + quad * 8);
          sv[jm] = __builtin_amdgcn_mfma_f32_16x16x32_bf16(kf, qf[ks], sv[jm], 0, 0, 0);
        }
      }
      __builtin_amdgcn_s_setprio(0);

      // ---- online softmax with defer-max (THR=8): lane holds 16 scores
      float p[4][4];
      float pmax = -INFINITY;
      #pragma unroll
      for (int jm = 0; jm < 4; jm++)
        #pragma unroll
        for (int reg = 0; reg < 4; reg++) {
          float v = sv[jm][reg] * scale;
          int key = kb + jm * 16 + quad * 4 + reg;
          if (key > q) v = -1e30f;
          p[jm][reg] = v;
          pmax = fmaxf(pmax, v);
        }
      pmax = fmaxf(pmax, __shfl_xor(pmax, 16));
      pmax = fmaxf(pmax, __shfl_xor(pmax, 32));
      if (!__all(pmax - m_i <= 8.f)) {        // rescale only on real growth
        float mnew = fmaxf(m_i, pmax);
        float alpha = __expf(m_i - mnew);
        l_i *= alpha;
        #pragma unroll
        for (int ht = 0; ht < 8; ht++) o[ht] *= alpha;
        m_i = mnew;
      }
      float sum = 0.f;
      #pragma unroll
      for (int jm = 0; jm < 4; jm++)
        #pragma unroll
        for (int reg = 0; reg < 4; reg++) { p[jm][reg] = __expf(p[jm][reg] - m_i); sum += p[jm][reg]; }
      sum += __shfl_xor(sum, 16);
      sum += __shfl_xor(sum, 32);
      l_i += sum;

      #pragma unroll
      for (int jm = 0; jm < 4; jm++) {
        ushort4 pk;
        pk.x = f2bf(p[jm][0]); pk.y = f2bf(p[jm][1]);
        pk.z = f2bf(p[jm][2]); pk.w = f2bf(p[jm][3]);
        *(ushort4*)(plw + l15 * 72 + jm * 16 + quad * 4) = pk;
      }

      __builtin_amdgcn_s_setprio(1);
      #pragma unroll
      for (int ks2 = 0; ks2 < 2; ks2++) {
        short8 pf = *(const short8*)(plw + l15 * 72 + ks2 * 32 + quad * 8);
        #pragma unroll
        for (int ht = 0; ht < 8; ht++) {
          short8 vf = *(const short8*)(Vtl + (ht * 16 + l15) * 72 + ks2 * 32 + quad * 8);
          o[ht] = __builtin_amdgcn_mfma_f32_16x16x32_bf16(vf, pf, o[ht], 0, 0, 0);
        }
      }
      __builtin_amdgcn_s_setprio(0);
    }

    float inv = 1.0f / l_i;
    size_t base = ((size_t)(bb * S_ + q)) * H_ + h * HD_ + quad * 4;
    #pragma unroll
    for (int ht = 0; ht < 8; ht++) {
      ushort4 ov;
      ov.x = f2bf(o[ht][0] * inv); ov.y = f2bf(o[ht][1] * inv);
      ov.z = f2bf(o[ht][2] * inv); ov.w = f2bf(o[ht][3] * inv);
      *(ushort4*)(ow + base + ht * 16) = ov;
    }
  }
}

// ---------------------------------------------------------------- launcher
extern "C" void kernel_launch(void* const* d_in, const int* in_sizes, int n_in,
                              void* d_out, int out_size, void* d_ws, size_t ws_size,
                              hipStream_t stream) {
  (void)in_sizes; (void)n_in; (void)out_size; (void)ws_size;
  const float* x      = (const float*)d_in[0];
  const float* ln_w   = (const float*)d_in[1];
  const float* ln_b   = (const float*)d_in[2];
  const float* attn_w = (const float*)d_in[3];
  const float* attn_b = (const float*)d_in[4];
  const float* proj_w = (const float*)d_in[5];
  const float* proj_b = (const float*)d_in[6];
  float* out = (float*)d_out;

  char* ws = (char*)d_ws;
  size_t off = 0;
  auto alloc = [&](size_t bytes) {
    char* p = ws + off;
    off += (bytes + 255) & ~(size_t)255;
    return p;
  };
  unsigned short* xn     = (unsigned short*)alloc((size_t)M_ * H_ * 2);
  unsigned short* wqkvt  = (unsigned short*)alloc((size_t)N3_ * H_ * 2);
  unsigned short* wprojt = (unsigned short*)alloc((size_t)H_ * H_ * 2);
  unsigned short* qws    = (unsigned short*)alloc((size_t)M_ * H_ * 2);
  unsigned short* kws    = (unsigned short*)alloc((size_t)M_ * H_ * 2);
  unsigned short* vtws   = (unsigned short*)alloc((size_t)M_ * H_ * 2);
  unsigned short* attn_out = xn;   // xn dead after qkv_gemm — alias

  ln_kernel<<<M_, 256, 0, stream>>>(x, ln_w, ln_b, xn);
  transpose_f2b<<<dim3(N3_ / 32, H_ / 32), 256, 0, stream>>>(attn_w, wqkvt, H_, N3_);
  transpose_f2b<<<dim3(H_ / 32, H_ / 32), 256, 0, stream>>>(proj_w, wprojt, H_, H_);
  qkv_gemm<<<dim3(N3_ / 256, M_ / 256), 512, 0, stream>>>(xn, wqkvt, attn_b, qws, kws, vtws);
  attn_kernel<<<dim3(NQT_ / 2, B_ * NH_), 256, 0, stream>>>(qws, kws, vtws, attn_out);
  proj_gemm<<<dim3(H_ / 256, M_ / 256), 512, 0, stream>>>(attn_out, wprojt, proj_b, x, out);
}

// Round 3
// 610.095 us; speedup vs baseline: 1.0248x; 1.0248x over previous
//
#include <hip/hip_runtime.h>
#include <stdint.h>
#include <math.h>

#define B_  4
#define S_  2048
#define H_  2048
#define NH_ 16
#define HD_ 128
#define M_  (B_*S_)     // 8192 rows
#define N3_ (3*H_)      // 6144
#define NQT_ (S_/64)    // 32 q-tiles of 64 rows
#define NT_ (H_/64)     // 32 K-tiles for the GEMMs

typedef __attribute__((ext_vector_type(8))) short short8;
typedef __attribute__((ext_vector_type(4))) float floatx4;
typedef unsigned int u32;

__device__ __forceinline__ unsigned short f2bf(float f) {
  unsigned u = __float_as_uint(f);
  u += 0x7FFF + ((u >> 16) & 1);          // round-to-nearest-even
  return (unsigned short)(u >> 16);
}

// async 16B global -> LDS (global_load_lds_dwordx4). LDS dest must be
// wave-uniform base + lane*16 (no per-lane scatter / padding!).
__device__ __forceinline__ void gl2lds16(const void* g, void* l) {
  __builtin_amdgcn_global_load_lds(
      (const __attribute__((address_space(1))) u32*)g,
      (__attribute__((address_space(3))) u32*)l, 16, 0, 0);
}

// ---------------------------------------------------------------- LayerNorm
__global__ __launch_bounds__(256) void ln_kernel(
    const float* __restrict__ x, const float* __restrict__ w,
    const float* __restrict__ b, unsigned short* __restrict__ xn) {
  int row = blockIdx.x;
  int t = threadIdx.x;
  const float* xr = x + (size_t)row * H_;
  float4 v0 = *(const float4*)(xr + t * 4);
  float4 v1 = *(const float4*)(xr + 1024 + t * 4);
  float s  = v0.x + v0.y + v0.z + v0.w + v1.x + v1.y + v1.z + v1.w;
  float sq = v0.x*v0.x + v0.y*v0.y + v0.z*v0.z + v0.w*v0.w
           + v1.x*v1.x + v1.y*v1.y + v1.z*v1.z + v1.w*v1.w;
  #pragma unroll
  for (int m = 32; m; m >>= 1) { s += __shfl_xor(s, m); sq += __shfl_xor(sq, m); }
  __shared__ float red[8];
  int wv = t >> 6;
  if ((t & 63) == 0) { red[wv * 2] = s; red[wv * 2 + 1] = sq; }
  __syncthreads();
  s  = red[0] + red[2] + red[4] + red[6];
  sq = red[1] + red[3] + red[5] + red[7];
  float mu  = s * (1.0f / H_);
  float var = sq * (1.0f / H_) - mu * mu;
  float rs  = rsqrtf(var + 1e-5f);

  float4 w0 = *(const float4*)(w + t * 4);
  float4 b0 = *(const float4*)(b + t * 4);
  float4 w1 = *(const float4*)(w + 1024 + t * 4);
  float4 b1 = *(const float4*)(b + 1024 + t * 4);
  ushort4 o0, o1;
  o0.x = f2bf((v0.x - mu) * rs * w0.x + b0.x);
  o0.y = f2bf((v0.y - mu) * rs * w0.y + b0.y);
  o0.z = f2bf((v0.z - mu) * rs * w0.z + b0.z);
  o0.w = f2bf((v0.w - mu) * rs * w0.w + b0.w);
  o1.x = f2bf((v1.x - mu) * rs * w1.x + b1.x);
  o1.y = f2bf((v1.y - mu) * rs * w1.y + b1.y);
  o1.z = f2bf((v1.z - mu) * rs * w1.z + b1.z);
  o1.w = f2bf((v1.w - mu) * rs * w1.w + b1.w);
  unsigned short* orow = xn + (size_t)row * H_;
  *(ushort4*)(orow + t * 4) = o0;
  *(ushort4*)(orow + 1024 + t * 4) = o1;
}

// ------------------------------------------- fp32 [R][C] -> bf16 [C][R] (Wt)
__global__ __launch_bounds__(256) void transpose_f2b(
    const float* __restrict__ in, unsigned short* __restrict__ out,
    int R, int C) {
  __shared__ float tile[32][33];
  int tx = threadIdx.x & 31, ty = threadIdx.x >> 5;   // ty 0..7
  int c0 = blockIdx.x * 32, r0 = blockIdx.y * 32;
  #pragma unroll
  for (int i = 0; i < 32; i += 8)
    tile[ty + i][tx] = in[(size_t)(r0 + ty + i) * C + c0 + tx];
  __syncthreads();
  #pragma unroll
  for (int i = 0; i < 32; i += 8)
    out[(size_t)(c0 + ty + i) * R + r0 + tx] = f2bf(tile[tx][ty + i]);
}

// ===================================================================
// 256x256 GEMM core, register-pipelined (R2).
// Quadrants q0=(Aeven,b01) q1=(Aeven,b23) q2=(Aodd,b01) q3=(Aodd,b23);
// ds_reads for q+1 issue BEFORE MFMA cluster q (separate reg sets ->
// WAR-safe), counted lgkmcnt gates each cluster: LDS pipe runs under
// MFMA instead of barrier-serialized. One s_barrier + one vmcnt(0) per
// tile; the vmcnt(0) drains stages issued one full tile (~2500cy) ago.
// Stage-safety: every wave lgkmcnt(0)-drains its buf reads before the
// barrier; stages into the retired buffer issue only post-barrier.
// ===================================================================
__device__ __forceinline__ void gemm256_acc(
    const unsigned short* __restrict__ A, const unsigned short* __restrict__ Bt,
    int m0, int n0, unsigned short (*sh)[16384], floatx4 (&acc)[8][4]) {
  const int t = threadIdx.x;
  const int lane = t & 63, wv = t >> 6;
  const int l15 = lane & 15, quad = lane >> 4;
  const int wm = wv >> 2, wn = wv & 3;
  const int x7 = l15 & 7;

  // read-side bases (shorts); frag (i,ks) = base + i*1024 + kx[ks]
  const int aRB = (wm * 128 + l15) * 64;
  const int bRB = (wn * 64 + l15) * 64;
  const int kx0 = ((0 + quad) ^ x7) * 8;
  const int kx1 = ((4 + quad) ^ x7) * 8;

  // stage-side: thread t covers (row r = t>>3, chunk cc = t&7) of each region
  const int r = t >> 3, cc = t & 7;
  const int scol = (cc ^ (r & 7)) * 8;                 // swizzled SOURCE chunk
  const unsigned short* aSrc = A + (size_t)(m0 + r) * H_ + scol;
  const int btr = (r >> 5) * 64 + (r & 31);            // B-j01 tile row
  const unsigned short* bSrc = Bt + (size_t)(n0 + btr) * H_ + scol;
  const int aDst = t * 8;                              // shorts, lane-linear
  const int bDst = (r >> 5) * 4096 + (r & 31) * 64 + cc * 8;

  // sh[buf*2] = A tile, sh[buf*2+1] = B tile
  auto stageAll = [&](int kt, int buf) {               // 8 gl2lds, one K-tile
    const unsigned short* sa = aSrc + kt * 64;
    const unsigned short* sb = bSrc + kt * 64;
    unsigned short* da = sh[buf * 2] + aDst;
    unsigned short* db = sh[buf * 2 + 1] + bDst;
    gl2lds16(sa, da);                                  // A rows [0,64)
    gl2lds16(sa + (size_t)128 * H_, da + 8192);        // A rows [128,192)
    gl2lds16(sa + (size_t)64 * H_, da + 4096);         // A rows [64,128)
    gl2lds16(sa + (size_t)192 * H_, da + 12288);       // A rows [192,256)
    gl2lds16(sb, db);                                  // B j01 lower
    gl2lds16(sb + (size_t)128 * H_, db + 8192);        // B j01 upper
    gl2lds16(sb + (size_t)32 * H_, db + 2048);         // B j23 lower
    gl2lds16(sb + (size_t)160 * H_, db + 10240);       // B j23 upper
  };

  short8 aE[4][2], aO[4][2], b01[2][2], b23[2][2];
  auto readAE = [&](const unsigned short* Ab) {
    #pragma unroll
    for (int i = 0; i < 4; ++i) {
      aE[i][0] = *(const short8*)(Ab + aRB + i * 1024 + kx0);
      aE[i][1] = *(const short8*)(Ab + aRB + i * 1024 + kx1);
    }
  };
  auto readAO = [&](const unsigned short* Ab) {
    #pragma unroll
    for (int i = 0; i < 4; ++i) {
      aO[i][0] = *(const short8*)(Ab + aRB + (i + 4) * 1024 + kx0);
      aO[i][1] = *(const short8*)(Ab + aRB + (i + 4) * 1024 + kx1);
    }
  };
  auto readB01 = [&](const unsigned short* Bb) {
    #pragma unroll
    for (int j = 0; j < 2; ++j) {
      b01[j][0] = *(const short8*)(Bb + bRB + j * 1024 + kx0);
      b01[j][1] = *(const short8*)(Bb + bRB + j * 1024 + kx1);
    }
  };
  auto readB23 = [&](const unsigned short* Bb) {
    #pragma unroll
    for (int j = 0; j < 2; ++j) {
      b23[j][0] = *(const short8*)(Bb + bRB + (j + 2) * 1024 + kx0);
      b23[j][1] = *(const short8*)(Bb + bRB + (j + 2) * 1024 + kx1);
    }
  };

  #pragma unroll
  for (int i = 0; i < 8; i++)
    #pragma unroll
    for (int j = 0; j < 4; j++) acc[i][j] = (floatx4){0.f, 0.f, 0.f, 0.f};

  // prologue: stage tiles 0 and 1; wait tile0; first q0 reads
  stageAll(0, 0);
  stageAll(1, 1);
  asm volatile("s_waitcnt vmcnt(8)" ::: "memory");     // tile0 landed
  __builtin_amdgcn_s_barrier();
  readAE(sh[0]); readB01(sh[1]);                       // q0 frags, tile0

  for (int n = 0; n < NT_; ++n) {
    const int buf = n & 1;
    const unsigned short* Ab = sh[buf * 2];
    const unsigned short* Bb = sh[buf * 2 + 1];

    // issue q1 reads (4), then MFMA q0 once its 12 frags landed
    readB23(Bb);
    asm volatile("s_waitcnt lgkmcnt(4)" ::: "memory");
    __builtin_amdgcn_sched_barrier(0);
    __builtin_amdgcn_s_setprio(1);
    #pragma unroll
    for (int i = 0; i < 4; ++i)
      #pragma unroll
      for (int j = 0; j < 2; ++j) {
        acc[i][j] = __builtin_amdgcn_mfma_f32_16x16x32_bf16(aE[i][0], b01[j][0], acc[i][j], 0, 0, 0);
        acc[i][j] = __builtin_amdgcn_mfma_f32_16x16x32_bf16(aE[i][1], b01[j][1], acc[i][j], 0, 0, 0);
      }
    __builtin_amdgcn_s_setprio(0);

    // issue q2 reads (8), then MFMA q1 once b23 landed
    readAO(Ab);
    asm volatile("s_waitcnt lgkmcnt(8)" ::: "memory");
    __builtin_amdgcn_sched_barrier(0);
    __builtin_amdgcn_s_setprio(1);
    #pragma unroll
    for (int i = 0; i < 4; ++i)
      #pragma unroll
      for (int j = 0; j < 2; ++j) {
        acc[i][j + 2] = __builtin_amdgcn_mfma_f32_16x16x32_bf16(aE[i][0], b23[j][0], acc[i][j + 2], 0, 0, 0);
        acc[i][j + 2] = __builtin_amdgcn_mfma_f32_16x16x32_bf16(aE[i][1], b23[j][1], acc[i][j + 2], 0, 0, 0);
      }
    __builtin_amdgcn_s_setprio(0);

    // MFMA q2 once aO landed (also drains all buf reads pre-barrier)
    asm volatile("s_waitcnt lgkmcnt(0)" ::: "memory");
    __builtin_amdgcn_sched_barrier(0);
    __builtin_amdgcn_s_setprio(1);
    #pragma unroll
    for (int i = 0; i < 4; ++i)
      #pragma unroll
      for (int j = 0; j < 2; ++j) {
        acc[i + 4][j] = __builtin_amdgcn_mfma_f32_16x16x32_bf16(aO[i][0], b01[j][0], acc[i + 4][j], 0, 0, 0);
        acc[i + 4][j] = __builtin_amdgcn_mfma_f32_16x16x32_bf16(aO[i][1], b01[j][1], acc[i + 4][j], 0, 0, 0);
      }
    __builtin_amdgcn_s_setprio(0);

    // buffer swap: stages(n+1) (issued one tile ago) landed; all waves'
    // reads of buf drained -> safe to restage buf post-barrier.
    asm volatile("s_waitcnt vmcnt(0)" ::: "memory");
    __builtin_amdgcn_s_barrier();
    if (n + 1 < NT_) { readAE(sh[(buf ^ 1) * 2]); readB01(sh[(buf ^ 1) * 2 + 1]); }
    if (n + 2 < NT_) stageAll(n + 2, buf);

    // MFMA q3 (regs only) overlaps next-tile q0 reads + stage issue
    __builtin_amdgcn_s_setprio(1);
    #pragma unroll
    for (int i = 0; i < 4; ++i)
      #pragma unroll
      for (int j = 0; j < 2; ++j) {
        acc[i + 4][j + 2] = __builtin_amdgcn_mfma_f32_16x16x32_bf16(aO[i][0], b23[j][0], acc[i + 4][j + 2], 0, 0, 0);
        acc[i + 4][j + 2] = __builtin_amdgcn_mfma_f32_16x16x32_bf16(aO[i][1], b23[j][1], acc[i + 4][j + 2], 0, 0, 0);
      }
    __builtin_amdgcn_s_setprio(0);
  }
}

// XCD-aware work mapping with L2-correct loop order. HW: block bid runs on
// XCD bid%8. XCD x owns m-panels [4x,4x+4) (A set = 4MB, L2-resident) and
// sweeps all n-panels n-OUTER m-INNER. Requires gridDim.y == 32.
__device__ __forceinline__ void xcd_map(int& m0, int& n0) {
  int bid = blockIdx.y * gridDim.x + blockIdx.x;
  int xcd = bid & 7, loc = bid >> 3;
  m0 = ((xcd << 2) | (loc & 3)) * 256;
  n0 = (loc >> 2) * 256;
}

// ---------------------------------------------------------------- QKV GEMM
__global__ __launch_bounds__(512, 2) void qkv_gemm(
    const unsigned short* __restrict__ A, const unsigned short* __restrict__ Bt,
    const float* __restrict__ bias,
    unsigned short* __restrict__ qw, unsigned short* __restrict__ kw,
    unsigned short* __restrict__ vtw) {
  __shared__ unsigned short sh[4][16384];   // 128 KiB
  int m0, n0;
  xcd_map(m0, n0);

  floatx4 acc[8][4];
  gemm256_acc(A, Bt, m0, n0, sh, acc);

  int t = threadIdx.x, lane = t & 63, wv = t >> 6;
  int l15 = lane & 15, quad = lane >> 4;
  int wm = wv >> 2, wn = wv & 3;
  int sec = n0 >> 11;                       // 0:Q 1:K 2:V (256 | 2048)
  #pragma unroll
  for (int j = 0; j < 4; ++j) {
    int nn = n0 + wn * 64 + j * 16 + l15;
    int h = (nn >> 7) & 15;
    int d = nn & 127;
    float bval = bias[nn];
    #pragma unroll
    for (int i = 0; i < 8; ++i) {
      int m = m0 + wm * 128 + i * 16 + quad * 4;   // 4 consecutive rows
      int bb = m >> 11, s = m & 2047;
      int bh = bb * NH_ + h;
      if (sec == 2) {
        ushort4 pv;
        pv.x = f2bf(acc[i][j][0] + bval); pv.y = f2bf(acc[i][j][1] + bval);
        pv.z = f2bf(acc[i][j][2] + bval); pv.w = f2bf(acc[i][j][3] + bval);
        *(ushort4*)(vtw + ((size_t)bh * HD_ + d) * S_ + s) = pv;
      } else {
        unsigned short* dst = (sec == 0 ? qw : kw) + ((size_t)bh * S_ + s) * HD_ + d;
        #pragma unroll
        for (int reg = 0; reg < 4; reg++)
          dst[(size_t)reg * HD_] = f2bf(acc[i][j][reg] + bval);
      }
    }
  }
}

// ----------------------------------------------------------- Proj GEMM + res
__global__ __launch_bounds__(512, 2) void proj_gemm(
    const unsigned short* __restrict__ A, const unsigned short* __restrict__ Bt,
    const float* __restrict__ bias, const float* __restrict__ resid,
    float* __restrict__ out) {
  __shared__ unsigned short sh[4][16384];
  int m0, n0;
  xcd_map(m0, n0);

  floatx4 acc[8][4];
  gemm256_acc(A, Bt, m0, n0, sh, acc);

  int t = threadIdx.x, lane = t & 63, wv = t >> 6;
  int l15 = lane & 15, quad = lane >> 4;
  int wm = wv >> 2, wn = wv & 3;
  #pragma unroll
  for (int j = 0; j < 4; ++j) {
    int nn = n0 + wn * 64 + j * 16 + l15;
    float bval = bias[nn];
    #pragma unroll
    for (int i = 0; i < 8; ++i) {
      int m = m0 + wm * 128 + i * 16 + quad * 4;
      #pragma unroll
      for (int reg = 0; reg < 4; ++reg)
        out[(size_t)(m + reg) * H_ + nn] =
            acc[i][j][reg] + bval + resid[(size_t)(m + reg) * H_ + nn];
    }
  }
}

// ------------------------------------------------------- causal flash attn
// R1: + s_setprio around MFMA clusters (T5) + defer-max THR=8 (T13)
__global__ __launch_bounds__(256) void attn_kernel(
    const unsigned short* __restrict__ qw, const unsigned short* __restrict__ kw,
    const unsigned short* __restrict__ vtw, unsigned short* __restrict__ ow) {
  __shared__ unsigned short Klds[64 * 136];   // [key 64][d 128 + pad]
  __shared__ unsigned short Vtl[128 * 72];    // [d 128][key 64 + pad]
  __shared__ unsigned short Pl[4][16 * 72];   // [wave][q 16][key 64 + pad]
  int pr = blockIdx.x, bh = blockIdx.y;
  int t = threadIdx.x, lane = t & 63, wv = t >> 6;
  int l15 = lane & 15, quad = lane >> 4;
  int h = bh & 15, bb = bh >> 4;

  const float scale = 0.08838834764831845f;
  int krr = t >> 4, kcc = (t & 15) * 8;       // K staging: 16 lanes/row
  int vdd = t >> 3, vss = (t & 7) * 8;        // Vt staging: 8 lanes/row
  unsigned short* plw = &Pl[wv][0];
  const unsigned short* kgb = kw + ((size_t)bh * S_ + krr) * HD_ + kcc;
  const unsigned short* vgb = vtw + ((size_t)bh * HD_ + vdd) * S_ + vss;

  short8 kreg[4], vreg[4];
  auto load_stage = [&](int kb) {
    #pragma unroll
    for (int c = 0; c < 4; c++) {
      kreg[c] = *(const short8*)(kgb + (size_t)(kb + c * 16) * HD_);
      vreg[c] = *(const short8*)(vgb + (size_t)(c * 32) * S_ + kb);
    }
  };

  #pragma unroll 1
  for (int half = 0; half < 2; half++) {
    int qt = half ? (NQT_ - 1 - pr) : pr;
    int qr = qt * 64 + wv * 16;
    int q = qr + l15;                         // this lane's q-row

    short8 qf[4];
    {
      const unsigned short* qbase = qw + ((size_t)bh * S_ + q) * HD_ + quad * 8;
      #pragma unroll
      for (int ks = 0; ks < 4; ks++)
        qf[ks] = *(const short8*)(qbase + ks * 32);
    }

    float m_i = -INFINITY, l_i = 0.f;
    floatx4 o[8];
    #pragma unroll
    for (int ht = 0; ht < 8; ht++) o[ht] = (floatx4){0.f, 0.f, 0.f, 0.f};

    load_stage(0);                            // prime the pipeline
    #pragma unroll 1
    for (int kt = 0; kt <= qt; kt++) {
      int kb = kt * 64;
      __syncthreads();                        // prev tile's LDS reads done
      #pragma unroll
      for (int c = 0; c < 4; c++) {
        *(short8*)(Klds + (c * 16 + krr) * 136 + kcc) = kreg[c];
        *(short8*)(Vtl + (c * 32 + vdd) * 72 + vss) = vreg[c];
      }
      __syncthreads();                        // tile visible to all waves
      if (kt < qt) load_stage(kb + 64);       // prefetch overlaps compute

      floatx4 sv[4];
      __builtin_amdgcn_s_setprio(1);
      #pragma unroll
      for (int jm = 0; jm < 4; jm++) {
        sv[jm] = (floatx4){0.f, 0.f, 0.f, 0.f};
        #pragma unroll
        for (int ks = 0; ks < 4; ks++) {
          short8 kf = *(const short8*)(Klds + (jm * 16 + l15) * 136 + ks * 32 + quad * 8);
          sv[jm] = __builtin_amdgcn_mfma_f32_16x16x32_bf16(kf, qf[ks], sv[jm], 0, 0, 0);
        }
      }
      __builtin_amdgcn_s_setprio(0);

      // ---- online softmax with defer-max (THR=8): lane holds 16 scores
      float p[4][4];
      float pmax = -INFINITY;
      #pragma unroll
      for (int jm = 0; jm < 4; jm++)
        #pragma unroll
        for (int reg = 0; reg < 4; reg++) {
          float v = sv[jm][reg] * scale;
          int key = kb + jm * 16 + quad * 4 + reg;
          if (key > q) v = -1e30f;
          p[jm][reg] = v;
          pmax = fmaxf(pmax, v);
        }
      pmax = fmaxf(pmax, __shfl_xor(pmax, 16));
      pmax = fmaxf(pmax, __shfl_xor(pmax, 32));
      if (!__all(pmax - m_i <= 8.f)) {        // rescale only on real growth
        float mnew = fmaxf(m_i, pmax);
        float alpha = __expf(m_i - mnew);
        l_i *= alpha;
        #pragma unroll
        for (int ht = 0; ht < 8; ht++) o[ht] *= alpha;
        m_i = mnew;
      }
      float sum = 0.f;
      #pragma unroll
      for (int jm = 0; jm < 4; jm++)
        #pragma unroll
        for (int reg = 0; reg < 4; reg++) { p[jm][reg] = __expf(p[jm][reg] - m_i); sum += p[jm][reg]; }
      sum += __shfl_xor(sum, 16);
      sum += __shfl_xor(sum, 32);
      l_i += sum;

      #pragma unroll
      for (int jm = 0; jm < 4; jm++) {
        ushort4 pk;
        pk.x = f2bf(p[jm][0]); pk.y = f2bf(p[jm][1]);
        pk.z = f2bf(p[jm][2]); pk.w = f2bf(p[jm][3]);
        *(ushort4*)(plw + l15 * 72 + jm * 16 + quad * 4) = pk;
      }

      __builtin_amdgcn_s_setprio(1);
      #pragma unroll
      for (int ks2 = 0; ks2 < 2; ks2++) {
        short8 pf = *(const short8*)(plw + l15 * 72 + ks2 * 32 + quad * 8);
        #pragma unroll
        for (int ht = 0; ht < 8; ht++) {
          short8 vf = *(const short8*)(Vtl + (ht * 16 + l15) * 72 + ks2 * 32 + quad * 8);
          o[ht] = __builtin_amdgcn_mfma_f32_16x16x32_bf16(vf, pf, o[ht], 0, 0, 0);
        }
      }
      __builtin_amdgcn_s_setprio(0);
    }

    float inv = 1.0f / l_i;
    size_t base = ((size_t)(bb * S_ + q)) * H_ + h * HD_ + quad * 4;
    #pragma unroll
    for (int ht = 0; ht < 8; ht++) {
      ushort4 ov;
      ov.x = f2bf(o[ht][0] * inv); ov.y = f2bf(o[ht][1] * inv);
      ov.z = f2bf(o[ht][2] * inv); ov.w = f2bf(o[ht][3] * inv);
      *(ushort4*)(ow + base + ht * 16) = ov;
    }
  }
}

// ---------------------------------------------------------------- launcher
extern "C" void kernel_launch(void* const* d_in, const int* in_sizes, int n_in,
                              void* d_out, int out_size, void* d_ws, size_t ws_size,
                              hipStream_t stream) {
  (void)in_sizes; (void)n_in; (void)out_size; (void)ws_size;
  const float* x      = (const float*)d_in[0];
  const float* ln_w   = (const float*)d_in[1];
  const float* ln_b   = (const float*)d_in[2];
  const float* attn_w = (const float*)d_in[3];
  const float* attn_b = (const float*)d_in[4];
  const float* proj_w = (const float*)d_in[5];
  const float* proj_b = (const float*)d_in[6];
  float* out = (float*)d_out;

  char* ws = (char*)d_ws;
  size_t off = 0;
  auto alloc = [&](size_t bytes) {
    char* p = ws + off;
    off += (bytes + 255) & ~(size_t)255;
    return p;
  };
  unsigned short* xn     = (unsigned short*)alloc((size_t)M_ * H_ * 2);
  unsigned short* wqkvt  = (unsigned short*)alloc((size_t)N3_ * H_ * 2);
  unsigned short* wprojt = (unsigned short*)alloc((size_t)H_ * H_ * 2);
  unsigned short* qws    = (unsigned short*)alloc((size_t)M_ * H_ * 2);
  unsigned short* kws    = (unsigned short*)alloc((size_t)M_ * H_ * 2);
  unsigned short* vtws   = (unsigned short*)alloc((size_t)M_ * H_ * 2);
  unsigned short* attn_out = xn;   // xn dead after qkv_gemm — alias

  ln_kernel<<<M_, 256, 0, stream>>>(x, ln_w, ln_b, xn);
  transpose_f2b<<<dim3(N3_ / 32, H_ / 32), 256, 0, stream>>>(attn_w, wqkvt, H_, N3_);
  transpose_f2b<<<dim3(H_ / 32, H_ / 32), 256, 0, stream>>>(proj_w, wprojt, H_, H_);
  qkv_gemm<<<dim3(N3_ / 256, M_ / 256), 512, 0, stream>>>(xn, wqkvt, attn_b, qws, kws, vtws);
  attn_kernel<<<dim3(NQT_ / 2, B_ * NH_), 256, 0, stream>>>(qws, kws, vtws, attn_out);
  proj_gemm<<<dim3(H_ / 256, M_ / 256), 512, 0, stream>>>(attn_out, wprojt, proj_b, x, out);
}